// Round 16
// baseline (317.435 us; speedup 1.0000x reference)
//
#include <hip/hip_runtime.h>
#include <math.h>

#define TT 3
#define LL 3
#define EE 50000
#define NN 1000000
#define RR 200
#define NRELC 401
#define HH 256
#define BB 8
#define KTOP 1000
#define SROW 24            // e-major state stride: s[e*24 + row], row = b*3+l
#define NBUCK 782          // buckets of 64 dests: ceil(50000/64)
#define BSH 6              // bucket shift
#define CSRN (2 * NN)      // total staged entries (1M fwd + 1M bwd)
#define STB 512            // stage blocks (per-block histogram sort)
#define SEGS 50176         // per-row ckey capacity (>= EE)
#define EBLK ((EE + 255) / 256)   // 196

__device__ __forceinline__ float sigmoidf_(float x) {
    if (x >= 0.f) { return 1.f / (1.f + expf(-x)); }
    float z = expf(x); return z / (1.f + z);
}

// ========== Phase A: LSTM GEMV + cell update FUSED (quadrant-strided rows) ==========
__global__ __launch_bounds__(256) void pre_fused(
    const int* __restrict__ input_r, const float* __restrict__ emb,
    const float* __restrict__ Wih_f, const float* __restrict__ bih_f, const float* __restrict__ bhh_f,
    const float* __restrict__ Wih_b, const float* __restrict__ bih_b, const float* __restrict__ bhh_b,
    float* __restrict__ preq, float* __restrict__ pree,
    float* __restrict__ hstate, float* __restrict__ cstate, float* __restrict__ hbuf2,
    const int* __restrict__ heads, const int* __restrict__ tails,
    unsigned* __restrict__ bh, int do_hist)
{
    if (blockIdx.x >= 384) {                  // -------- packed csr_hist --------
        if (!do_hist) return;
        __shared__ unsigned h[NBUCK];
        int tid = threadIdx.x;
        int bid = blockIdx.x - 384;           // 0..511
        for (int i = tid; i < NBUCK; i += 256) h[i] = 0u;
        __syncthreads();
        for (int i = bid * 256 + tid; i < NN; i += STB * 256) {
            atomicAdd(&h[tails[i] >> BSH], 1u);
            atomicAdd(&h[heads[i] >> BSH], 1u);
        }
        __syncthreads();
        for (int j = tid; j < NBUCK; j += 256)
            bh[(size_t)j * STB + bid] = h[j];
        return;
    }
    int wave = blockIdx.x * 4 + (threadIdx.x >> 6);   // 0..1535
    int lane = threadIdx.x & 63;
    int ld = wave >> 8;                       // 0..5 = l*2+dir
    int j  = wave & 255;
    int l = ld >> 1, dir = ld & 1;
    const float* Wih = (dir ? Wih_b : Wih_f) + (size_t)l * 4 * HH * HH;
    const float* bih = (dir ? bih_b : bih_f) + l * 4 * HH;
    const float* bhh = (dir ? bhh_b : bhh_f) + l * 4 * HH;

    float4 xf[9];
    for (int b = 0; b < 8; ++b) {
        int r = input_r[b];
        xf[b] = *(const float4*)(emb + (size_t)r * HH + lane * 4);
    }
    xf[8] = *(const float4*)(emb + (size_t)(NRELC - 1) * HH + lane * 4);

    float g4[4], ge4[4];
    for (int q = 0; q < 4; ++q) {
        int row = q * 256 + j;
        float4 w4 = *(const float4*)(Wih + (size_t)row * HH + lane * 4);
        float acc[9];
        #pragma unroll
        for (int c = 0; c < 9; ++c)
            acc[c] = w4.x * xf[c].x + w4.y * xf[c].y + w4.z * xf[c].z + w4.w * xf[c].w;
        #pragma unroll
        for (int off = 32; off > 0; off >>= 1)
            #pragma unroll
            for (int c = 0; c < 9; ++c) acc[c] += __shfl_xor(acc[c], off);
        float bsum = bih[row] + bhh[row];
        g4[q]  = (lane < 8 ? acc[lane] : 0.f) + bsum;
        ge4[q] = acc[8] + bsum;
        if (lane < 8) preq[((size_t)ld * 8 + lane) * 1024 + row] = g4[q];
        if (lane == 8) pree[(size_t)ld * 1024 + row] = ge4[q];
    }
    // step-0 cell update (c0 = 0 so the forget term drops)
    if (lane < 8) {
        float gi, gg, go;
        if (dir == 0) { gi = g4[0]; gg = g4[2]; go = g4[3]; }
        else          { gi = ge4[0]; gg = ge4[2]; go = ge4[3]; }   // e-channel input
        float c = sigmoidf_(gi) * tanhf(gg);
        float h = sigmoidf_(go) * tanhf(c);
        int g = (ld * 8 + lane) * 256 + j;
        cstate[g] = c;
        hstate[g] = h;
        if (dir == 0) hbuf2[(((size_t)ld * 8 + lane) * 3 + 0) * HH + j] = h;
    }
}

__global__ __launch_bounds__(256) void rec_fused(
    const float* __restrict__ Whh_f, const float* __restrict__ Whh_b,
    const float* __restrict__ preq, const float* __restrict__ pree,
    const float* __restrict__ hprev, float* __restrict__ hnext,
    float* __restrict__ cstate, float* __restrict__ hbuf2, int step)
{
    int wave = blockIdx.x * 4 + (threadIdx.x >> 6);   // 0..1535 (grid = 384)
    int lane = threadIdx.x & 63;
    int ld = wave >> 8, j = wave & 255;
    int l = ld >> 1, dir = ld & 1;
    const float* Whh = (dir ? Whh_b : Whh_f) + (size_t)l * 4 * HH * HH;
    bool use_e = (dir == 0) && (step == 3);   // dir1's e-step was step 0 (in pre_fused)

    float4 hf[8];
    for (int b = 0; b < 8; ++b)
        hf[b] = *(const float4*)(hprev + ((size_t)ld * 8 + b) * HH + lane * 4);

    float g4[4];
    for (int q = 0; q < 4; ++q) {
        int row = q * 256 + j;
        float4 w4 = *(const float4*)(Whh + (size_t)row * HH + lane * 4);
        float acc[8];
        #pragma unroll
        for (int b = 0; b < 8; ++b)
            acc[b] = w4.x * hf[b].x + w4.y * hf[b].y + w4.z * hf[b].z + w4.w * hf[b].w;
        #pragma unroll
        for (int off = 32; off > 0; off >>= 1)
            #pragma unroll
            for (int b = 0; b < 8; ++b) acc[b] += __shfl_xor(acc[b], off);
        if (lane < 8) {
            float pre = use_e ? pree[(size_t)ld * 1024 + row]
                              : preq[((size_t)ld * 8 + lane) * 1024 + row];
            g4[q] = acc[lane] + pre;
        }
    }
    if (lane < 8) {
        int g = (ld * 8 + lane) * 256 + j;
        float c = cstate[g];
        float iv = sigmoidf_(g4[0]), fv = sigmoidf_(g4[1]);
        float gg = tanhf(g4[2]),     ov = sigmoidf_(g4[3]);
        c = fv * c + iv * gg;
        float h = ov * tanhf(c);
        cstate[g] = c;
        hnext[g] = h;
        int t_out = dir ? (3 - step) : step;
        if (t_out <= 2) hbuf2[(((size_t)ld * 8 + lane) * 3 + t_out) * HH + j] = h;
    }
}

// logits (blocks <903); blocks >=903 (CSR): packed csr_scanb (per-bucket scan of bh).
__global__ __launch_bounds__(256) void logits_dot(
    const float* __restrict__ hbuf2, const float* __restrict__ linW,
    const float* __restrict__ linb, float* __restrict__ wbuf,
    unsigned* __restrict__ bh, unsigned* __restrict__ gcnt)
{
    int tid = threadIdx.x;
    if (blockIdx.x >= 903) {                  // -------- packed csr_scanb --------
        if (gcnt == nullptr) return;
        int bk = blockIdx.x - 903;            // 0..781
        unsigned a = bh[(size_t)bk * STB + 2 * tid];
        unsigned b = bh[(size_t)bk * STB + 2 * tid + 1];
        unsigned s = a + b;
        __shared__ unsigned sc[256];
        sc[tid] = s; __syncthreads();
        #pragma unroll
        for (int off = 1; off < 256; off <<= 1) {
            unsigned u = (tid >= off) ? sc[tid - off] : 0u;
            __syncthreads();
            sc[tid] += u;
            __syncthreads();
        }
        unsigned incl = sc[tid];
        unsigned ex = incl - s;               // exclusive at pair start
        bh[(size_t)bk * STB + 2 * tid]     = ex;
        bh[(size_t)bk * STB + 2 * tid + 1] = ex + a;
        if (tid == 255) gcnt[bk] = incl;      // bucket total
        return;
    }
    int wave = blockIdx.x * 4 + (tid >> 6);
    if (wave >= 3 * 3 * NRELC) return;
    int lane = tid & 63;
    int n = wave % NRELC;
    int tc = wave / NRELC;          // 0..8
    int t = tc / 3, chunk = tc % 3;
    const float4* wr = (const float4*)(linW + (size_t)n * 2 * HH + lane * 8);
    float4 w4a = wr[0], w4b = wr[1];
    float acc[8];
    #pragma unroll
    for (int i = 0; i < 8; ++i) {
        int combo = chunk * 8 + i;      // combo = b*3 + l
        int b = combo / 3, l = combo % 3;
        int ldh = (lane < 32) ? (l * 2 + 0) : (l * 2 + 1);
        const float* hsrc = hbuf2 + (((size_t)ldh * 8 + b) * 3 + t) * HH + (lane & 31) * 8;
        float4 f0 = *(const float4*)hsrc;
        float4 f1 = *(const float4*)(hsrc + 4);
        acc[i] = w4a.x * f0.x + w4a.y * f0.y + w4a.z * f0.z + w4a.w * f0.w
               + w4b.x * f1.x + w4b.y * f1.y + w4b.z * f1.z + w4b.w * f1.w;
    }
    #pragma unroll
    for (int off = 32; off > 0; off >>= 1)
        #pragma unroll
        for (int i = 0; i < 8; ++i) acc[i] += __shfl_xor(acc[i], off);
    if (lane < 8) {
        int combo = chunk * 8 + lane;
        wbuf[((size_t)t * 24 + combo) * NRELC + n] = acc[lane] + linb[n];
    }
}

// softmax (blocks <72; t=0 rows mirror into wT0).
// [72, 72+EBLK): maskT0 one-hot bits, zero maskT1/T2, arm cursors.
// [72+EBLK, 72+EBLK+STB): packed csr_stage2 — each block redundantly scans gcnt
// (782-elem exclusive scan in LDS) for gOff, then scatters its edge slice;
// block 0 publishes gOff to global for hop_bucket.
__global__ __launch_bounds__(256) void softmax_kernel(
    float* __restrict__ wbuf, float* __restrict__ wT0,
    int* __restrict__ maskT0, int* __restrict__ maskT1, int* __restrict__ maskT2,
    const int* __restrict__ input_x, unsigned* __restrict__ rowcnt,
    const int* __restrict__ heads, const int* __restrict__ tails,
    const int* __restrict__ tails2, const int* __restrict__ rels,
    const unsigned* __restrict__ bh, const unsigned* __restrict__ gcnt,
    unsigned* __restrict__ gOff, unsigned* __restrict__ staging)
{
    int tid = threadIdx.x;
    if (blockIdx.x >= 72 + EBLK) {                // -------- packed csr_stage2 --------
        int bid = blockIdx.x - (72 + EBLK);       // 0..511
        __shared__ unsigned sv[1024];
        __shared__ unsigned base[NBUCK];
        __shared__ unsigned cur[NBUCK];
        unsigned orig[4];
        #pragma unroll
        for (int k = 0; k < 4; ++k) {
            int j = tid + k * 256;
            unsigned v = (j < NBUCK) ? gcnt[j] : 0u;
            orig[k] = v; sv[j] = v;
        }
        __syncthreads();
        for (int off = 1; off < 1024; off <<= 1) {
            unsigned t4[4];
            #pragma unroll
            for (int k = 0; k < 4; ++k) {
                int j = tid + k * 256;
                t4[k] = (j >= off) ? sv[j - off] : 0u;
            }
            __syncthreads();
            #pragma unroll
            for (int k = 0; k < 4; ++k) sv[tid + k * 256] += t4[k];
            __syncthreads();
        }
        #pragma unroll
        for (int k = 0; k < 4; ++k) {
            int j = tid + k * 256;
            if (j < NBUCK) {
                unsigned ex = sv[j] - orig[k];    // exclusive bucket offset
                base[j] = ex + bh[(size_t)j * STB + bid];
                cur[j] = 0u;
                if (bid == 0) gOff[j] = ex;
            }
        }
        if (bid == 0 && tid == 0) gOff[NBUCK] = sv[1023];
        __syncthreads();
        for (int i = bid * 256 + tid; i < NN; i += STB * 256) {
            unsigned rl = (unsigned)rels[i];
            int h = heads[i], d1 = tails[i], t2 = tails2[i];
            unsigned p1 = base[d1 >> BSH] + atomicAdd(&cur[d1 >> BSH], 1u);
            if (p1 < (unsigned)CSRN)
                staging[p1] = ((unsigned)(d1 & 63) << 26) | ((unsigned)h << 9) | rl;
            unsigned p2 = base[h >> BSH] + atomicAdd(&cur[h >> BSH], 1u);
            if (p2 < (unsigned)CSRN)
                staging[p2] = ((unsigned)(h & 63) << 26) | ((unsigned)t2 << 9) | (rl + RR);
        }
        return;
    }
    if (blockIdx.x >= 72) {                       // -------- packed mask init --------
        if (maskT0 == nullptr) return;
        __shared__ int xs[8];
        if (tid < 8) xs[tid] = input_x[tid];
        if (blockIdx.x == 72 && tid < 24) rowcnt[tid] = 0u;
        __syncthreads();
        int e = (blockIdx.x - 72) * 256 + tid;
        if (e >= EE) return;
        int m = 0;
        #pragma unroll
        for (int b = 0; b < 8; ++b) if (e == xs[b]) m |= 1 << b;
        maskT0[e] = m;
        maskT1[e] = 0;
        maskT2[e] = 0;
        return;
    }
    int rowi = blockIdx.x;                        // t*24 + combo
    float* w = wbuf + (size_t)rowi * NRELC;
    __shared__ float red[256];
    float v0 = w[tid];
    float v1 = (tid + 256 < NRELC) ? w[tid + 256] : -1e30f;
    red[tid] = fmaxf(v0, v1); __syncthreads();
    for (int s2 = 128; s2 > 0; s2 >>= 1) {
        if (tid < s2) red[tid] = fmaxf(red[tid], red[tid + s2]);
        __syncthreads();
    }
    float m = red[0]; __syncthreads();
    float e0 = expf((v0 - m) * 0.1f);
    float e1 = (tid + 256 < NRELC) ? expf((v1 - m) * 0.1f) : 0.f;
    red[tid] = e0 + e1; __syncthreads();
    for (int s2 = 128; s2 > 0; s2 >>= 1) {
        if (tid < s2) red[tid] += red[tid + s2];
        __syncthreads();
    }
    float denom = red[0];
    float o0 = e0 / denom;
    w[tid] = o0;
    float o1 = 0.f;
    if (tid + 256 < NRELC) { o1 = e1 / denom; w[tid + 256] = o1; }
    if (wT0 != nullptr && rowi < 24) {            // t=0 rows -> transposed (rels only)
        if (tid < 2 * RR) wT0[(size_t)tid * SROW + rowi] = o0;
        if (tid + 256 < 2 * RR) wT0[(size_t)(tid + 256) * SROW + rowi] = o1;
    }
}

// ================= hop 0 (fallback path): fused zero-fill + one-hot seed =================
__global__ __launch_bounds__(256) void fill_seed(
    float* __restrict__ s, const int* __restrict__ input_x, const float* __restrict__ w0,
    unsigned* __restrict__ rowcnt)
{
    __shared__ int xs[8];
    __shared__ float wv[24];
    if (threadIdx.x < 8) xs[threadIdx.x] = input_x[threadIdx.x];
    if (threadIdx.x < 24) wv[threadIdx.x] = w0[(size_t)threadIdx.x * NRELC + (NRELC - 1)];
    if (blockIdx.x == 0 && threadIdx.x < 24) rowcnt[threadIdx.x] = 0u;
    __syncthreads();
    int i = blockIdx.x * 256 + threadIdx.x;
    if (i >= SROW * EE) return;
    int row = i % 24;
    int e = i / 24;
    s[i] = (e == xs[row / 3]) ? wv[row] : 0.f;
}

__global__ __launch_bounds__(256) void hop0_scan(
    const int* __restrict__ heads, const int* __restrict__ tails,
    const int* __restrict__ tails2, const int* __restrict__ rels,
    const int* __restrict__ input_x, const float* __restrict__ w0,
    float* __restrict__ s)
{
    __shared__ int xs[BB];
    if (threadIdx.x < BB) xs[threadIdx.x] = input_x[threadIdx.x];
    __syncthreads();
    int i = blockIdx.x * 256 + threadIdx.x;
    if (i >= NN) return;
    int h = heads[i], t2 = tails2[i];
    bool any = false;
    #pragma unroll
    for (int b = 0; b < BB; ++b) any = any || (h == xs[b]) || (t2 == xs[b]);
    if (!any) return;
    int tl = tails[i], rr = rels[i];
    for (int b = 0; b < BB; ++b) {
        if (h == xs[b])
            for (int l = 0; l < LL; ++l)
                atomicAdd(&s[(size_t)tl * SROW + b * 3 + l], w0[(b * 3 + l) * NRELC + rr]);
        if (t2 == xs[b])
            for (int l = 0; l < LL; ++l)
                atomicAdd(&s[(size_t)h * SROW + b * 3 + l], w0[(b * 3 + l) * NRELC + rr + RR]);
    }
}

// ====== hop-0 row sums + contiguous nonzero compaction (fallback path) ======
__global__ __launch_bounds__(256) void rowsum_compact(
    const float* __restrict__ s, float* __restrict__ partial,
    unsigned* __restrict__ ckey, unsigned* __restrict__ rowcnt, int do_compact)
{
    __shared__ float acc[24];
    __shared__ unsigned lkey[24][168];
    __shared__ unsigned lcnt[24];
    __shared__ unsigned lbase[24];
    int tid = threadIdx.x;
    if (tid < 24) { acc[tid] = 0.f; lcnt[tid] = 0u; }
    __syncthreads();
    int gidx = blockIdx.x * 256 + tid;        // 384*256 = 98304
    int row = gidx % 24;
    float a = 0.f;
    const int total = SROW * EE;              // 1,200,000
    for (int k = 0; k < 13; ++k) {
        long i = (long)gidx + (long)k * 98304;
        if (i < total) {
            float v = s[i];
            a += v;
            if (do_compact && __float_as_uint(v) != 0u) {
                unsigned slot = atomicAdd(&lcnt[row], 1u);
                slot = min(slot, 167u);        // defensive (invariant: <=143)
                lkey[row][slot] = __float_as_uint(v);
            }
        }
    }
    if (do_compact) {
        __syncthreads();
        if (tid < 24) {
            unsigned c = min(lcnt[tid], 168u);
            lcnt[tid] = c;
            lbase[tid] = min(atomicAdd(&rowcnt[tid], c), (unsigned)SEGS);
        }
        __syncthreads();
        int r = tid % 24;
        int nthr = (r < 16) ? 11 : 10;
        unsigned cnt = lcnt[r], base = lbase[r];
        if (base + cnt > (unsigned)SEGS) cnt = (unsigned)SEGS - base;   // defensive
        for (unsigned j = (unsigned)(tid / 24); j < cnt; j += nthr)
            ckey[(size_t)r * SEGS + base + j] = lkey[r][j];
        __syncthreads();
    }
    atomicAdd(&acc[row], a);
    __syncthreads();
    if (tid < 24) partial[blockIdx.x * 24 + tid] = acc[tid];
}

// 24 blocks: ordered 384-add (fallback hop-0); emits wsc.
__global__ __launch_bounds__(256) void rowsum_fin(
    const float* __restrict__ partial, float* __restrict__ sums,
    const float* __restrict__ w_t, float* __restrict__ wsc,
    float* __restrict__ wTg)
{
    int r = blockIdx.x;
    int tid = threadIdx.x;
    __shared__ float sa;
    if (tid == 0) {
        float a = 0.f;
        for (int j = 0; j < 384; ++j) a += partial[j * 24 + r];
        a = fmaxf(a, 1e-7f);
        sums[r] = a;
        sa = a;
    }
    __syncthreads();
    if (w_t != nullptr) {
        float a = sa;
        for (int i = tid; i < NRELC; i += 256) {
            float v = w_t[(size_t)r * NRELC + i] / a;
            wsc[(size_t)r * NRELC + i] = v;
            if (wTg != nullptr && i < 2 * RR) wTg[(size_t)i * SROW + r] = v;
        }
    }
}

// ====== MERGED hop epilogue (48 blocks x 512) ======
__global__ __launch_bounds__(512) void hop_epi(
    const unsigned* __restrict__ ckey, const unsigned* __restrict__ cent,
    unsigned* __restrict__ rowcnt, float* __restrict__ th,
    int* __restrict__ mask_next,
    const float* __restrict__ partial2, float* __restrict__ sums,
    const float* __restrict__ w_t, float* __restrict__ wsc,
    float* __restrict__ wTg)
{
    int tid = threadIdx.x;
    if (blockIdx.x >= 24) {                   // -------- rowsum_fin2 half --------
        int r = blockIdx.x - 24;
        __shared__ float red[256];
        __shared__ float sa;
        if (tid < 256) {                      // keep 256-lane reduce order (FP-stable)
            float a = 0.f;
            for (int g = tid; g < NBUCK; g += 256) a += partial2[(size_t)g * 24 + r];
            red[tid] = a;
        }
        __syncthreads();
        for (int s2 = 128; s2 > 0; s2 >>= 1) {
            if (tid < s2) red[tid] += red[tid + s2];
            __syncthreads();
        }
        if (tid == 0) { sa = fmaxf(red[0], 1e-7f); sums[r] = sa; }
        __syncthreads();
        float aa = sa;
        for (int i = tid; i < NRELC; i += 512) {
            float v = w_t[(size_t)r * NRELC + i] / aa;
            wsc[(size_t)r * NRELC + i] = v;
            if (i < 2 * RR) wTg[(size_t)i * SROW + r] = v;
        }
        return;
    }
    // -------- topk half --------
    int row = blockIdx.x;
    const unsigned* keys = ckey + (size_t)row * SEGS;
    int n = min((int)rowcnt[row], SEGS);
    __shared__ unsigned hist[256];
    __shared__ int red[256];
    __shared__ int sh_bin, sh_rem;
    unsigned prefix = 0;
    int remk = KTOP;
    int iters = (n + 511) / 512;
    int lane = tid & 63;
    for (int round = 0; round < 4; ++round) {
        if (tid < 256) hist[tid] = 0u;
        __syncthreads();
        int shift = 24 - 8 * round;
        for (int it = 0; it < iters; ++it) {
            int i = it * 512 + tid;
            bool valid = (i < n);
            unsigned key = valid ? keys[i] : 0u;
            valid = valid && (round == 0 || (key >> (shift + 8)) == prefix);
            unsigned bin = valid ? ((key >> shift) & 255u) : 0u;
            unsigned long long peers = __ballot(valid);
            #pragma unroll
            for (int bit = 0; bit < 8; ++bit) {
                unsigned long long bm = __ballot(valid && ((bin >> bit) & 1u));
                peers &= ((bin >> bit) & 1u) ? bm : ~bm;
            }
            if (valid) {
                unsigned long long lower = peers & ((1ull << lane) - 1ull);
                if (lower == 0ull)
                    atomicAdd(&hist[bin], (unsigned)__popcll(peers));
            }
        }
        __syncthreads();
        if (tid < 256) red[tid] = (int)hist[tid];
        __syncthreads();
        for (int off = 1; off < 256; off <<= 1) {   // inclusive suffix scan
            int v = 0;
            if (tid < 256 && tid + off < 256) v = red[tid + off];
            __syncthreads();
            if (tid < 256) red[tid] += v;
            __syncthreads();
        }
        if (tid == 0) { sh_bin = 0; sh_rem = remk; }  // default: k-th lies among zeros
        __syncthreads();
        if (tid < 256) {
            int cnt = (int)hist[tid];
            int above = (tid == 255) ? 0 : red[tid + 1];
            if (above < remk && above + cnt >= remk) { sh_bin = tid; sh_rem = remk - above; }
        }
        __syncthreads();
        prefix = (prefix << 8) | (unsigned)sh_bin;
        remk = sh_rem;
        __syncthreads();
    }
    if (tid == 0) th[row] = __uint_as_float(prefix);
    {
        const unsigned* ents = cent + (size_t)row * SEGS;
        int bit = 1 << (row / 3);
        for (int i = tid; i < n; i += 512) {
            if (keys[i] >= prefix) {
                unsigned e = ents[i];
                if (e < (unsigned)EE) atomicOr(&mask_next[e], bit);
            }
        }
        if (tid == 0) rowcnt[row] = 0u;       // re-arm compact cursor for next hop
    }
}

// ====== fallback topk (contiguous lists, zero+write same mask) ======
__global__ __launch_bounds__(512) void topk_select(
    const unsigned* __restrict__ ckey, unsigned* __restrict__ rowcnt,
    float* __restrict__ th, int* __restrict__ mask)
{
    int row = blockIdx.x, tid = threadIdx.x;
    {
        int per = (EE + 23) / 24;
        int e0 = row * per, e1 = min(e0 + per, EE);
        for (int e = e0 + tid; e < e1; e += 512) mask[e] = 0;
    }
    const unsigned* keys = ckey + (size_t)row * SEGS;
    int n = min((int)rowcnt[row], SEGS);
    __shared__ unsigned hist[256];
    __shared__ int red[256];
    __shared__ int sh_bin, sh_rem;
    unsigned prefix = 0;
    int remk = KTOP;
    int iters = (n + 511) / 512;
    int lane = tid & 63;
    for (int round = 0; round < 4; ++round) {
        if (tid < 256) hist[tid] = 0u;
        __syncthreads();
        int shift = 24 - 8 * round;
        for (int it = 0; it < iters; ++it) {
            int i = it * 512 + tid;
            bool valid = (i < n);
            unsigned key = valid ? keys[i] : 0u;
            valid = valid && (round == 0 || (key >> (shift + 8)) == prefix);
            unsigned bin = valid ? ((key >> shift) & 255u) : 0u;
            unsigned long long peers = __ballot(valid);
            #pragma unroll
            for (int bit = 0; bit < 8; ++bit) {
                unsigned long long bm = __ballot(valid && ((bin >> bit) & 1u));
                peers &= ((bin >> bit) & 1u) ? bm : ~bm;
            }
            if (valid) {
                unsigned long long lower = peers & ((1ull << lane) - 1ull);
                if (lower == 0ull)
                    atomicAdd(&hist[bin], (unsigned)__popcll(peers));
            }
        }
        __syncthreads();
        if (tid < 256) red[tid] = (int)hist[tid];
        __syncthreads();
        for (int off = 1; off < 256; off <<= 1) {
            int v = 0;
            if (tid < 256 && tid + off < 256) v = red[tid + off];
            __syncthreads();
            if (tid < 256) red[tid] += v;
            __syncthreads();
        }
        if (tid == 0) { sh_bin = 0; sh_rem = remk; }
        __syncthreads();
        if (tid < 256) {
            int cnt = (int)hist[tid];
            int above = (tid == 255) ? 0 : red[tid + 1];
            if (above < remk && above + cnt >= remk) { sh_bin = tid; sh_rem = remk - above; }
        }
        __syncthreads();
        prefix = (prefix << 8) | (unsigned)sh_bin;
        remk = sh_rem;
        __syncthreads();
    }
    if (tid == 0) th[row] = __uint_as_float(prefix);
}

// ======= fallback prune (writes x + identity-seeded s) =======
__global__ __launch_bounds__(256) void prune_flat(
    float* __restrict__ s, const float* __restrict__ th,
    const float* __restrict__ wsc, float* __restrict__ x, int* __restrict__ mask,
    unsigned* __restrict__ rowcnt, int write_s)
{
    __shared__ float ths[24], w4s[24];
    if (threadIdx.x < 24) {
        ths[threadIdx.x] = th[threadIdx.x];
        w4s[threadIdx.x] = wsc[threadIdx.x * NRELC + (NRELC - 1)];  // w400/sum
    }
    if (blockIdx.x == 0 && threadIdx.x < 24) rowcnt[threadIdx.x] = 0u;  // re-arm cursors
    __syncthreads();
    int i = blockIdx.x * 256 + threadIdx.x;
    if (i >= SROW * EE) return;
    int row = i % 24;
    int e = i / 24;
    float v = s[i];
    float xv = (v >= ths[row]) ? v : 0.f;
    x[i] = xv;
    if (write_s) s[i] = w4s[row] * xv;
    if (xv > 0.f) atomicOr(&mask[e], 1 << (row / 3));
}

// ============ FALLBACK (ws too small): fused masked scatter ============
__global__ __launch_bounds__(256) void hop_scan(
    const int* __restrict__ heads, const int* __restrict__ tails,
    const int* __restrict__ tails2, const int* __restrict__ rels,
    const int* __restrict__ mask, const float* __restrict__ x,
    const float* __restrict__ wsc, float* __restrict__ s)
{
    int gid = blockIdx.x * 256 + threadIdx.x;
    int i = gid >> 3;
    if (i >= NN) return;
    int b = gid & 7;
    int h = heads[i], t2 = tails2[i];
    int mh = mask[h], mt = mask[t2];
    bool ah = (mh >> b) & 1;
    bool at = (mt >> b) & 1;
    if (!(ah || at)) return;
    int tl = tails[i], rr = rels[i];
    int row = b * 3;
    if (ah) {
        float v0 = x[(size_t)h * SROW + row];
        float v1 = x[(size_t)h * SROW + row + 1];
        float v2 = x[(size_t)h * SROW + row + 2];
        if (v0 != 0.f) atomicAdd(&s[(size_t)tl * SROW + row],     v0 * wsc[(row)     * NRELC + rr]);
        if (v1 != 0.f) atomicAdd(&s[(size_t)tl * SROW + row + 1], v1 * wsc[(row + 1) * NRELC + rr]);
        if (v2 != 0.f) atomicAdd(&s[(size_t)tl * SROW + row + 2], v2 * wsc[(row + 2) * NRELC + rr]);
    }
    if (at) {
        float v0 = x[(size_t)t2 * SROW + row];
        float v1 = x[(size_t)t2 * SROW + row + 1];
        float v2 = x[(size_t)t2 * SROW + row + 2];
        if (v0 != 0.f) atomicAdd(&s[(size_t)h * SROW + row],     v0 * wsc[(row)     * NRELC + rr + RR]);
        if (v1 != 0.f) atomicAdd(&s[(size_t)h * SROW + row + 1], v1 * wsc[(row + 1) * NRELC + rr + RR]);
        if (v2 != 0.f) atomicAdd(&s[(size_t)h * SROW + row + 2], v2 * wsc[(row + 2) * NRELC + rr + RR]);
    }
}

// ===== hops 0..2: bucket gather, fused identity+store+rowsum+compact =====
__global__ __launch_bounds__(256) void hop_bucket(
    const unsigned* __restrict__ gOff, const unsigned* __restrict__ staging,
    const int* __restrict__ mask, const float* __restrict__ sprev,
    const float* __restrict__ th, const int* __restrict__ input_x,
    const float* __restrict__ wT, const float* __restrict__ wsc,
    float* __restrict__ snext, float* __restrict__ partial2,
    unsigned* __restrict__ ckey, unsigned* __restrict__ cent,
    unsigned* __restrict__ rowcnt, int do_compact, int is_t0)
{
    __shared__ float sl[64][24];              // 6KB accumulation tile
    __shared__ float w4s[24];
    __shared__ float ths[24];
    __shared__ int   xs8[8];
    __shared__ float acc24[24];
    __shared__ unsigned lcnt[24];
    __shared__ unsigned lbase[24];
    __shared__ unsigned lkey[24][64];         // 6KB compact keys
    __shared__ unsigned lent[24][64];         // 6KB compact entities
    int bk = blockIdx.x, tid = threadIdx.x;
    for (int i = tid; i < 64 * 24; i += 256) ((float*)sl)[i] = 0.f;
    if (tid < 24) {
        w4s[tid] = wsc[tid * NRELC + (NRELC - 1)];
        ths[tid] = is_t0 ? 0.f : th[tid];
        acc24[tid] = 0.f;
        lcnt[tid] = 0u;
    }
    if (tid < 8) xs8[tid] = is_t0 ? input_x[tid] : 0;
    __syncthreads();
    unsigned j0 = gOff[bk], j1 = gOff[bk + 1];
    for (unsigned j = j0 + tid; j < j1; j += 256) {
        unsigned p = staging[j];
        int src = (int)((p >> 9) & 0xFFFFu);
        int m = mask[src];
        if (!m) continue;
        int dl = (int)(p >> 26);
        int rel = (int)(p & 511u);
        const float* wr = wT + (size_t)rel * SROW;
        if (is_t0) {
            while (m) {
                int b = __ffs(m) - 1; m &= m - 1;
                int r = b * 3;
                atomicAdd(&sl[dl][r],     wr[r]);
                atomicAdd(&sl[dl][r + 1], wr[r + 1]);
                atomicAdd(&sl[dl][r + 2], wr[r + 2]);
            }
        } else {
            const float* xsrow = sprev + (size_t)src * SROW;
            while (m) {
                int b = __ffs(m) - 1; m &= m - 1;
                int r = b * 3;
                float x0 = xsrow[r];     x0 = (x0 >= ths[r])     ? x0 : 0.f;
                float x1 = xsrow[r + 1]; x1 = (x1 >= ths[r + 1]) ? x1 : 0.f;
                float x2 = xsrow[r + 2]; x2 = (x2 >= ths[r + 2]) ? x2 : 0.f;
                atomicAdd(&sl[dl][r],     x0 * wr[r]);
                atomicAdd(&sl[dl][r + 1], x1 * wr[r + 1]);
                atomicAdd(&sl[dl][r + 2], x2 * wr[r + 2]);
            }
        }
    }
    __syncthreads();
    int e0 = bk * 64;
    for (int idx = tid; idx < 64 * 24; idx += 256) {
        int el = idx / 24, row = idx % 24;    // idx order == s layout -> coalesced store
        int e = e0 + el;
        if (e >= EE) continue;
        float xv;
        if (is_t0) {
            xv = (e == xs8[row / 3]) ? 1.f : 0.f;
        } else {
            float u = sprev[(size_t)e * SROW + row];
            xv = (u >= ths[row]) ? u : 0.f;
        }
        float v = sl[el][row] + w4s[row] * xv;
        snext[(size_t)e * SROW + row] = v;
        atomicAdd(&acc24[row], v);            // LDS
        if (do_compact && __float_as_uint(v) != 0u) {
            unsigned slot = atomicAdd(&lcnt[row], 1u);
            slot = min(slot, 63u);            // defensive (invariant: <=64)
            lkey[row][slot] = __float_as_uint(v);
            lent[row][slot] = (unsigned)e;
        }
    }
    __syncthreads();
    if (tid < 24) partial2[(size_t)bk * 24 + tid] = acc24[tid];
    if (do_compact) {
        if (tid < 24) {
            unsigned c = min(lcnt[tid], 64u);
            lcnt[tid] = c;
            lbase[tid] = min(atomicAdd(&rowcnt[tid], c), (unsigned)SEGS);
        }
        __syncthreads();
        int r = tid % 24;
        int nthr = (r < 16) ? 11 : 10;
        unsigned cnt = lcnt[r], base = lbase[r];
        if (base + cnt > (unsigned)SEGS) cnt = (unsigned)SEGS - base;   // defensive
        for (unsigned j = (unsigned)(tid / 24); j < cnt; j += nthr) {
            ckey[(size_t)r * SEGS + base + j] = lkey[r][j];
            cent[(size_t)r * SEGS + base + j] = lent[r][j];
        }
    }
}

// ===== final (fallback; reads precomputed sums) =====
__global__ void final_kernel(const float* __restrict__ s, const float* __restrict__ sums,
                             float* __restrict__ out) {
    __shared__ float ss[24];
    if (threadIdx.x < 24) ss[threadIdx.x] = sums[threadIdx.x];
    __syncthreads();
    int e = blockIdx.x * 256 + threadIdx.x;
    if (e >= EE) return;
    const float* se = s + (size_t)e * SROW;
    #pragma unroll
    for (int b = 0; b < 8; ++b)
        out[(size_t)b * EE + e] = se[b * 3] / ss[b * 3]
                                + se[b * 3 + 1] / ss[b * 3 + 1]
                                + se[b * 3 + 2] / ss[b * 3 + 2];
}

// ===== final (CSR): each block redundantly reduces partial2 -> sums (24 x 8-lane
// shfl groups, L2-hot), then normalizes. Deletes the last rowsum_fin2 dispatch. =====
__global__ __launch_bounds__(256) void final_fused(
    const float* __restrict__ s, const float* __restrict__ partial2,
    float* __restrict__ out)
{
    __shared__ float ss[24];
    int tid = threadIdx.x;
    if (tid < 192) {
        int r = tid >> 3, sub = tid & 7;
        float a = 0.f;
        for (int g = sub; g < NBUCK; g += 8) a += partial2[(size_t)g * 24 + r];
        a += __shfl_xor(a, 1);
        a += __shfl_xor(a, 2);
        a += __shfl_xor(a, 4);
        if (sub == 0) ss[r] = fmaxf(a, 1e-7f);
    }
    __syncthreads();
    int e = blockIdx.x * 256 + tid;
    if (e >= EE) return;
    const float* se = s + (size_t)e * SROW;
    #pragma unroll
    for (int b = 0; b < 8; ++b)
        out[(size_t)b * EE + e] = se[b * 3] / ss[b * 3]
                                + se[b * 3 + 1] / ss[b * 3 + 1]
                                + se[b * 3 + 2] / ss[b * 3 + 2];
}

extern "C" void kernel_launch(void* const* d_in, const int* in_sizes, int n_in,
                              void* d_out, int out_size, void* d_ws, size_t ws_size,
                              hipStream_t stream)
{
    const int*   input_x  = (const int*)d_in[0];
    const int*   input_r  = (const int*)d_in[1];
    const int*   e2triple = (const int*)d_in[2];
    const int*   triple2e = (const int*)d_in[3];
    const int*   r2triple = (const int*)d_in[4];
    const float* emb      = (const float*)d_in[5];
    const float* Wih_f    = (const float*)d_in[6];
    const float* Whh_f    = (const float*)d_in[7];
    const float* bih_f    = (const float*)d_in[8];
    const float* bhh_f    = (const float*)d_in[9];
    const float* Wih_b    = (const float*)d_in[10];
    const float* Whh_b    = (const float*)d_in[11];
    const float* bih_b    = (const float*)d_in[12];
    const float* bhh_b    = (const float*)d_in[13];
    const float* linW     = (const float*)d_in[14];
    const float* linb     = (const float*)d_in[15];

    const int* heads  = e2triple;
    const int* tails2 = e2triple + 2 * (size_t)NN;
    const int* tails  = triple2e + (size_t)NN;
    const int* rels   = r2triple;

    // workspace layout (~30 MB; poison fill shows ws >= 256 MB)
    float* ws      = (float*)d_ws;
    float* hbuf    = ws;                          // 36864
    float* wbuf    = hbuf + 36864;                // 28872
    float* sstA    = wbuf + 28872;                // 1200000 (e-major [E][24])
    float* sstB    = sstA + 1200000;              // 1200000
    float* sums    = sstB + 1200000;              // 24
    float* th      = sums + 24;                   // 24
    int*   maskT0  = (int*)(th + 24);             // 50000
    int*   maskT1  = maskT0 + EE;                 // 50000
    int*   maskT2  = maskT1 + EE;                 // 50000
    float* partial = (float*)(maskT2 + EE);       // 384*24 = 9216
    unsigned* rowcnt  = (unsigned*)(partial + 9216);  // 32
    float* partial2   = (float*)(rowcnt + 32);    // 782*24 = 18768
    unsigned* ckey    = (unsigned*)(partial2 + NBUCK * 24); // 24*50176 = 1,204,224
    unsigned* cent    = ckey + 24 * (size_t)SEGS; // 1,204,224 compact entity IDs
    unsigned* bh      = cent + 24 * (size_t)SEGS; // 782*512 = 400,384
    unsigned* gcnt    = bh + (size_t)NBUCK * STB; // 784
    unsigned* gOff    = gcnt + 784;               // 800 (NBUCK+1 used)
    unsigned* staging = gOff + 800;               // 2,000,000 (own region)
    float*    wT      = (float*)(staging + CSRN); // 9600 transposed scaled weights
    float*    wT0     = wT + 9600;                // 9600 transposed UNSCALED t0 weights
    const size_t NEED = (size_t)((wT0 + 9600) - ws) * 4;
    const bool use_csr = (ws_size >= NEED);
    // aliases (phase-A scratch inside sstA; dead before hop_bucket t0 writes it)
    float* wsc     = hbuf;                        // 9624, dead after logits_dot
    float* preq    = sstA;                        // 49152
    float* pree    = preq + 49152;                // 6144
    float* hstateA = pree + 6144;                 // 12288
    float* hstateB = hstateA + 12288;             // 12288
    float* cstate  = hstateB + 12288;             // 12288

    float* out = (float*)d_out;
    const int SBLK  = (SROW * EE + 255) / 256;    // 4688
    const int NBLK  = (NN + 255) / 256;           // 3907
    const int N8BLK = (NN * 8) / 256;             // 31250

    // ---- Phase A (fused LSTM cell updates; csr_hist packed into pre_fused) ----
    pre_fused<<<896, 256, 0, stream>>>(input_r, emb, Wih_f, bih_f, bhh_f,
                                       Wih_b, bih_b, bhh_b, preq, pree,
                                       hstateA, cstate, hbuf,
                                       heads, tails, bh, use_csr ? 1 : 0);
    rec_fused<<<384, 256, 0, stream>>>(Whh_f, Whh_b, preq, pree, hstateA, hstateB,
                                       cstate, hbuf, 1);
    rec_fused<<<384, 256, 0, stream>>>(Whh_f, Whh_b, preq, pree, hstateB, hstateA,
                                       cstate, hbuf, 2);
    rec_fused<<<384, 256, 0, stream>>>(Whh_f, Whh_b, preq, pree, hstateA, hstateB,
                                       cstate, hbuf, 3);

    if (use_csr) {
        // logits + packed csr_scanb (blocks >= 903)
        logits_dot<<<903 + NBUCK, 256, 0, stream>>>(hbuf, linW, linb, wbuf, bh, gcnt);
        // softmax + mask init + packed csr_stage2 (incl. per-block gOff scan)
        softmax_kernel<<<72 + EBLK + STB, 256, 0, stream>>>(
            wbuf, wT0, maskT0, maskT1, maskT2, input_x, rowcnt,
            heads, tails, tails2, rels, bh, gcnt, gOff, staging);
        // ---- hop 0: bucket gather with virtual one-hot input ----
        hop_bucket<<<NBUCK, 256, 0, stream>>>(gOff, staging, maskT0, nullptr, nullptr,
                                              input_x, wT0, wbuf, sstA, partial2,
                                              ckey, cent, rowcnt, 1, 1);
        hop_epi<<<48, 512, 0, stream>>>(ckey, cent, rowcnt, th, maskT1,
                                        partial2, sums, wbuf + 1 * 24 * NRELC, wsc, wT);
        // t=1: sstA -> sstB
        hop_bucket<<<NBUCK, 256, 0, stream>>>(gOff, staging, maskT1, sstA, th,
                                              input_x, wT, wsc, sstB, partial2,
                                              ckey, cent, rowcnt, 1, 0);
        hop_epi<<<48, 512, 0, stream>>>(ckey, cent, rowcnt, th, maskT2,
                                        partial2, sums, wbuf + 2 * 24 * NRELC, wsc, wT);
        // t=2: sstB -> sstA
        hop_bucket<<<NBUCK, 256, 0, stream>>>(gOff, staging, maskT2, sstB, th,
                                              input_x, wT, wsc, sstA, partial2,
                                              ckey, cent, rowcnt, 0, 0);
        // final: fused sums-reduce + normalize
        final_fused<<<EBLK, 256, 0, stream>>>(sstA, partial2, out);
    } else {
        logits_dot<<<903, 256, 0, stream>>>(hbuf, linW, linb, wbuf, nullptr, nullptr);
        softmax_kernel<<<72, 256, 0, stream>>>(wbuf, nullptr, nullptr, nullptr, nullptr,
                                               input_x, rowcnt, heads, tails, tails2,
                                               rels, bh, gcnt, gOff, staging);
        // ---- fallback: proven scatter path (xst = sstA as x buffer) ----
        float* xst = sstA;
        float* sst = sstB;
        int* mask = maskT0;
        fill_seed<<<SBLK, 256, 0, stream>>>(sst, input_x, wbuf, rowcnt);
        hop0_scan<<<NBLK, 256, 0, stream>>>(heads, tails, tails2, rels, input_x, wbuf, sst);
        rowsum_compact<<<384, 256, 0, stream>>>(sst, partial, ckey, rowcnt, 1);
        rowsum_fin<<<24, 256, 0, stream>>>(partial, sums, wbuf + 1 * 24 * NRELC, wsc, nullptr);
        for (int t = 1; t < TT; ++t) {
            topk_select<<<24, 512, 0, stream>>>(ckey, rowcnt, th, mask);
            prune_flat<<<SBLK, 256, 0, stream>>>(sst, th, wsc, xst, mask, rowcnt, 1);
            hop_scan<<<N8BLK, 256, 0, stream>>>(heads, tails, tails2, rels, mask, xst, wsc, sst);
            rowsum_compact<<<384, 256, 0, stream>>>(sst, partial, ckey, rowcnt,
                                                    (t + 1 < TT) ? 1 : 0);
            const float* w_next = (t + 1 < TT) ? (wbuf + (size_t)(t + 1) * 24 * NRELC) : nullptr;
            rowsum_fin<<<24, 256, 0, stream>>>(partial, sums, w_next, wsc, nullptr);
        }
        final_kernel<<<EBLK, 256, 0, stream>>>(sst, sums, out);
    }
}

// Round 17
// 288.157 us; speedup vs baseline: 1.1016x; 1.1016x over previous
//
#include <hip/hip_runtime.h>
#include <math.h>

#define TT 3
#define LL 3
#define EE 50000
#define NN 1000000
#define RR 200
#define NRELC 401
#define HH 256
#define BB 8
#define KTOP 1000
#define SROW 24            // e-major state stride: s[e*24 + row], row = b*3+l
#define NBUCK 782          // buckets of 64 dests: ceil(50000/64)
#define BSH 6              // bucket shift
#define CSRN (2 * NN)      // total staged entries (1M fwd + 1M bwd)
#define STB 512            // stage blocks (per-block histogram sort)
#define SEGS 50176         // per-row ckey capacity (>= EE)

__device__ __forceinline__ float sigmoidf_(float x) {
    if (x >= 0.f) { return 1.f / (1.f + expf(-x)); }
    float z = expf(x); return z / (1.f + z);
}

// ========== Phase A: LSTM GEMV + cell update FUSED (quadrant-strided rows) ==========
__global__ __launch_bounds__(256) void pre_fused(
    const int* __restrict__ input_r, const float* __restrict__ emb,
    const float* __restrict__ Wih_f, const float* __restrict__ bih_f, const float* __restrict__ bhh_f,
    const float* __restrict__ Wih_b, const float* __restrict__ bih_b, const float* __restrict__ bhh_b,
    float* __restrict__ preq, float* __restrict__ pree,
    float* __restrict__ hstate, float* __restrict__ cstate, float* __restrict__ hbuf2,
    const int* __restrict__ heads, const int* __restrict__ tails,
    unsigned* __restrict__ bh, int do_hist)
{
    if (blockIdx.x >= 384) {                  // -------- packed csr_hist --------
        if (!do_hist) return;
        __shared__ unsigned h[NBUCK];
        int tid = threadIdx.x;
        int bid = blockIdx.x - 384;           // 0..511
        for (int i = tid; i < NBUCK; i += 256) h[i] = 0u;
        __syncthreads();
        for (int i = bid * 256 + tid; i < NN; i += STB * 256) {
            atomicAdd(&h[tails[i] >> BSH], 1u);
            atomicAdd(&h[heads[i] >> BSH], 1u);
        }
        __syncthreads();
        for (int j = tid; j < NBUCK; j += 256)
            bh[(size_t)j * STB + bid] = h[j];
        return;
    }
    int wave = blockIdx.x * 4 + (threadIdx.x >> 6);   // 0..1535
    int lane = threadIdx.x & 63;
    int ld = wave >> 8;                       // 0..5 = l*2+dir
    int j  = wave & 255;
    int l = ld >> 1, dir = ld & 1;
    const float* Wih = (dir ? Wih_b : Wih_f) + (size_t)l * 4 * HH * HH;
    const float* bih = (dir ? bih_b : bih_f) + l * 4 * HH;
    const float* bhh = (dir ? bhh_b : bhh_f) + l * 4 * HH;

    float4 xf[9];
    for (int b = 0; b < 8; ++b) {
        int r = input_r[b];
        xf[b] = *(const float4*)(emb + (size_t)r * HH + lane * 4);
    }
    xf[8] = *(const float4*)(emb + (size_t)(NRELC - 1) * HH + lane * 4);

    float g4[4], ge4[4];
    for (int q = 0; q < 4; ++q) {
        int row = q * 256 + j;
        float4 w4 = *(const float4*)(Wih + (size_t)row * HH + lane * 4);
        float acc[9];
        #pragma unroll
        for (int c = 0; c < 9; ++c)
            acc[c] = w4.x * xf[c].x + w4.y * xf[c].y + w4.z * xf[c].z + w4.w * xf[c].w;
        #pragma unroll
        for (int off = 32; off > 0; off >>= 1)
            #pragma unroll
            for (int c = 0; c < 9; ++c) acc[c] += __shfl_xor(acc[c], off);
        float bsum = bih[row] + bhh[row];
        g4[q]  = (lane < 8 ? acc[lane] : 0.f) + bsum;
        ge4[q] = acc[8] + bsum;
        if (lane < 8) preq[((size_t)ld * 8 + lane) * 1024 + row] = g4[q];
        if (lane == 8) pree[(size_t)ld * 1024 + row] = ge4[q];
    }
    // step-0 cell update (c0 = 0 so the forget term drops)
    if (lane < 8) {
        float gi, gg, go;
        if (dir == 0) { gi = g4[0]; gg = g4[2]; go = g4[3]; }
        else          { gi = ge4[0]; gg = ge4[2]; go = ge4[3]; }   // e-channel input
        float c = sigmoidf_(gi) * tanhf(gg);
        float h = sigmoidf_(go) * tanhf(c);
        int g = (ld * 8 + lane) * 256 + j;
        cstate[g] = c;
        hstate[g] = h;
        if (dir == 0) hbuf2[(((size_t)ld * 8 + lane) * 3 + 0) * HH + j] = h;
    }
}

__global__ __launch_bounds__(256) void rec_fused(
    const float* __restrict__ Whh_f, const float* __restrict__ Whh_b,
    const float* __restrict__ preq, const float* __restrict__ pree,
    const float* __restrict__ hprev, float* __restrict__ hnext,
    float* __restrict__ cstate, float* __restrict__ hbuf2, int step)
{
    int wave = blockIdx.x * 4 + (threadIdx.x >> 6);   // 0..1535 (grid = 384)
    int lane = threadIdx.x & 63;
    int ld = wave >> 8, j = wave & 255;
    int l = ld >> 1, dir = ld & 1;
    const float* Whh = (dir ? Whh_b : Whh_f) + (size_t)l * 4 * HH * HH;
    bool use_e = (dir == 0) && (step == 3);   // dir1's e-step was step 0 (in pre_fused)

    float4 hf[8];
    for (int b = 0; b < 8; ++b)
        hf[b] = *(const float4*)(hprev + ((size_t)ld * 8 + b) * HH + lane * 4);

    float g4[4];
    for (int q = 0; q < 4; ++q) {
        int row = q * 256 + j;
        float4 w4 = *(const float4*)(Whh + (size_t)row * HH + lane * 4);
        float acc[8];
        #pragma unroll
        for (int b = 0; b < 8; ++b)
            acc[b] = w4.x * hf[b].x + w4.y * hf[b].y + w4.z * hf[b].z + w4.w * hf[b].w;
        #pragma unroll
        for (int off = 32; off > 0; off >>= 1)
            #pragma unroll
            for (int b = 0; b < 8; ++b) acc[b] += __shfl_xor(acc[b], off);
        if (lane < 8) {
            float pre = use_e ? pree[(size_t)ld * 1024 + row]
                              : preq[((size_t)ld * 8 + lane) * 1024 + row];
            g4[q] = acc[lane] + pre;
        }
    }
    if (lane < 8) {
        int g = (ld * 8 + lane) * 256 + j;
        float c = cstate[g];
        float iv = sigmoidf_(g4[0]), fv = sigmoidf_(g4[1]);
        float gg = tanhf(g4[2]),     ov = sigmoidf_(g4[3]);
        c = fv * c + iv * gg;
        float h = ov * tanhf(c);
        cstate[g] = c;
        hnext[g] = h;
        int t_out = dir ? (3 - step) : step;
        if (t_out <= 2) hbuf2[(((size_t)ld * 8 + lane) * 3 + t_out) * HH + j] = h;
    }
}

__global__ __launch_bounds__(256) void logits_dot(
    const float* __restrict__ hbuf2, const float* __restrict__ linW,
    const float* __restrict__ linb, float* __restrict__ wbuf)
{
    int wave = blockIdx.x * 4 + (threadIdx.x >> 6);
    if (wave >= 3 * 3 * NRELC) return;
    int lane = threadIdx.x & 63;
    int n = wave % NRELC;
    int tc = wave / NRELC;          // 0..8
    int t = tc / 3, chunk = tc % 3;
    const float4* wr = (const float4*)(linW + (size_t)n * 2 * HH + lane * 8);
    float4 w4a = wr[0], w4b = wr[1];
    float acc[8];
    #pragma unroll
    for (int i = 0; i < 8; ++i) {
        int combo = chunk * 8 + i;      // combo = b*3 + l
        int b = combo / 3, l = combo % 3;
        int ldh = (lane < 32) ? (l * 2 + 0) : (l * 2 + 1);
        const float* hsrc = hbuf2 + (((size_t)ldh * 8 + b) * 3 + t) * HH + (lane & 31) * 8;
        float4 f0 = *(const float4*)hsrc;
        float4 f1 = *(const float4*)(hsrc + 4);
        acc[i] = w4a.x * f0.x + w4a.y * f0.y + w4a.z * f0.z + w4a.w * f0.w
               + w4b.x * f1.x + w4b.y * f1.y + w4b.z * f1.z + w4b.w * f1.w;
    }
    #pragma unroll
    for (int off = 32; off > 0; off >>= 1)
        #pragma unroll
        for (int i = 0; i < 8; ++i) acc[i] += __shfl_xor(acc[i], off);
    if (lane < 8) {
        int combo = chunk * 8 + lane;
        wbuf[((size_t)t * 24 + combo) * NRELC + n] = acc[lane] + linb[n];
    }
}

// softmax (blocks <72); t=0 rows mirror into transposed unscaled wT0.
// Blocks >=72 (CSR mode): build maskT0 one-hot bits, zero maskT1/T2, arm cursors.
__global__ __launch_bounds__(256) void softmax_kernel(
    float* __restrict__ wbuf, float* __restrict__ wT0,
    int* __restrict__ maskT0, int* __restrict__ maskT1, int* __restrict__ maskT2,
    const int* __restrict__ input_x, unsigned* __restrict__ rowcnt)
{
    int tid = threadIdx.x;
    if (blockIdx.x >= 72) {                       // -------- packed mask init --------
        if (maskT0 == nullptr) return;
        __shared__ int xs[8];
        if (tid < 8) xs[tid] = input_x[tid];
        if (blockIdx.x == 72 && tid < 24) rowcnt[tid] = 0u;
        __syncthreads();
        int e = (blockIdx.x - 72) * 256 + tid;
        if (e >= EE) return;
        int m = 0;
        #pragma unroll
        for (int b = 0; b < 8; ++b) if (e == xs[b]) m |= 1 << b;
        maskT0[e] = m;
        maskT1[e] = 0;
        maskT2[e] = 0;
        return;
    }
    int rowi = blockIdx.x;                        // t*24 + combo
    float* w = wbuf + (size_t)rowi * NRELC;
    __shared__ float red[256];
    float v0 = w[tid];
    float v1 = (tid + 256 < NRELC) ? w[tid + 256] : -1e30f;
    red[tid] = fmaxf(v0, v1); __syncthreads();
    for (int s2 = 128; s2 > 0; s2 >>= 1) {
        if (tid < s2) red[tid] = fmaxf(red[tid], red[tid + s2]);
        __syncthreads();
    }
    float m = red[0]; __syncthreads();
    float e0 = expf((v0 - m) * 0.1f);
    float e1 = (tid + 256 < NRELC) ? expf((v1 - m) * 0.1f) : 0.f;
    red[tid] = e0 + e1; __syncthreads();
    for (int s2 = 128; s2 > 0; s2 >>= 1) {
        if (tid < s2) red[tid] += red[tid + s2];
        __syncthreads();
    }
    float denom = red[0];
    float o0 = e0 / denom;
    w[tid] = o0;
    float o1 = 0.f;
    if (tid + 256 < NRELC) { o1 = e1 / denom; w[tid + 256] = o1; }
    if (wT0 != nullptr && rowi < 24) {            // t=0 rows -> transposed (rels only)
        if (tid < 2 * RR) wT0[(size_t)tid * SROW + rowi] = o0;
        if (tid + 256 < 2 * RR) wT0[(size_t)(tid + 256) * SROW + rowi] = o1;
    }
}

// ================= hop 0 (fallback path): fused zero-fill + one-hot seed =================
__global__ __launch_bounds__(256) void fill_seed(
    float* __restrict__ s, const int* __restrict__ input_x, const float* __restrict__ w0,
    unsigned* __restrict__ rowcnt)
{
    __shared__ int xs[8];
    __shared__ float wv[24];
    if (threadIdx.x < 8) xs[threadIdx.x] = input_x[threadIdx.x];
    if (threadIdx.x < 24) wv[threadIdx.x] = w0[(size_t)threadIdx.x * NRELC + (NRELC - 1)];
    if (blockIdx.x == 0 && threadIdx.x < 24) rowcnt[threadIdx.x] = 0u;
    __syncthreads();
    int i = blockIdx.x * 256 + threadIdx.x;
    if (i >= SROW * EE) return;
    int row = i % 24;
    int e = i / 24;
    s[i] = (e == xs[row / 3]) ? wv[row] : 0.f;
}

__global__ __launch_bounds__(256) void hop0_scan(
    const int* __restrict__ heads, const int* __restrict__ tails,
    const int* __restrict__ tails2, const int* __restrict__ rels,
    const int* __restrict__ input_x, const float* __restrict__ w0,
    float* __restrict__ s)
{
    __shared__ int xs[BB];
    if (threadIdx.x < BB) xs[threadIdx.x] = input_x[threadIdx.x];
    __syncthreads();
    int i = blockIdx.x * 256 + threadIdx.x;
    if (i >= NN) return;
    int h = heads[i], t2 = tails2[i];
    bool any = false;
    #pragma unroll
    for (int b = 0; b < BB; ++b) any = any || (h == xs[b]) || (t2 == xs[b]);
    if (!any) return;
    int tl = tails[i], rr = rels[i];
    for (int b = 0; b < BB; ++b) {
        if (h == xs[b])
            for (int l = 0; l < LL; ++l)
                atomicAdd(&s[(size_t)tl * SROW + b * 3 + l], w0[(b * 3 + l) * NRELC + rr]);
        if (t2 == xs[b])
            for (int l = 0; l < LL; ++l)
                atomicAdd(&s[(size_t)h * SROW + b * 3 + l], w0[(b * 3 + l) * NRELC + rr + RR]);
    }
}

// ====== hop-0 row sums + contiguous nonzero compaction (fallback path) ======
__global__ __launch_bounds__(256) void rowsum_compact(
    const float* __restrict__ s, float* __restrict__ partial,
    unsigned* __restrict__ ckey, unsigned* __restrict__ rowcnt, int do_compact)
{
    __shared__ float acc[24];
    __shared__ unsigned lkey[24][168];
    __shared__ unsigned lcnt[24];
    __shared__ unsigned lbase[24];
    int tid = threadIdx.x;
    if (tid < 24) { acc[tid] = 0.f; lcnt[tid] = 0u; }
    __syncthreads();
    int gidx = blockIdx.x * 256 + tid;        // 384*256 = 98304
    int row = gidx % 24;
    float a = 0.f;
    const int total = SROW * EE;              // 1,200,000
    for (int k = 0; k < 13; ++k) {
        long i = (long)gidx + (long)k * 98304;
        if (i < total) {
            float v = s[i];
            a += v;
            if (do_compact && __float_as_uint(v) != 0u) {
                unsigned slot = atomicAdd(&lcnt[row], 1u);
                slot = min(slot, 167u);        // defensive (invariant: <=143)
                lkey[row][slot] = __float_as_uint(v);
            }
        }
    }
    if (do_compact) {
        __syncthreads();
        if (tid < 24) {
            unsigned c = min(lcnt[tid], 168u);
            lcnt[tid] = c;
            lbase[tid] = min(atomicAdd(&rowcnt[tid], c), (unsigned)SEGS);
        }
        __syncthreads();
        int r = tid % 24;
        int nthr = (r < 16) ? 11 : 10;
        unsigned cnt = lcnt[r], base = lbase[r];
        if (base + cnt > (unsigned)SEGS) cnt = (unsigned)SEGS - base;   // defensive
        for (unsigned j = (unsigned)(tid / 24); j < cnt; j += nthr)
            ckey[(size_t)r * SEGS + base + j] = lkey[r][j];
        __syncthreads();
    }
    atomicAdd(&acc[row], a);
    __syncthreads();
    if (tid < 24) partial[blockIdx.x * 24 + tid] = acc[tid];
}

// 24 blocks: ordered 384-add (fallback hop-0); emits wsc (+wT transposed scaled weights).
__global__ __launch_bounds__(256) void rowsum_fin(
    const float* __restrict__ partial, float* __restrict__ sums,
    const float* __restrict__ w_t, float* __restrict__ wsc,
    float* __restrict__ wTg)
{
    int r = blockIdx.x;
    int tid = threadIdx.x;
    __shared__ float sa;
    if (tid == 0) {
        float a = 0.f;
        for (int j = 0; j < 384; ++j) a += partial[j * 24 + r];
        a = fmaxf(a, 1e-7f);
        sums[r] = a;
        sa = a;
    }
    __syncthreads();
    if (w_t != nullptr) {
        float a = sa;
        for (int i = tid; i < NRELC; i += 256) {
            float v = w_t[(size_t)r * NRELC + i] / a;
            wsc[(size_t)r * NRELC + i] = v;
            if (wTg != nullptr && i < 2 * RR) wTg[(size_t)i * SROW + r] = v;
        }
    }
}

// 24 blocks: reduce hop_bucket's per-block partials (final sums only in CSR path).
__global__ __launch_bounds__(256) void rowsum_fin2(
    const float* __restrict__ partial2, float* __restrict__ sums,
    const float* __restrict__ w_t, float* __restrict__ wsc,
    float* __restrict__ wTg)
{
    int r = blockIdx.x;
    int tid = threadIdx.x;
    __shared__ float red[256];
    float a = 0.f;
    for (int g = tid; g < NBUCK; g += 256) a += partial2[(size_t)g * 24 + r];
    red[tid] = a; __syncthreads();
    for (int s2 = 128; s2 > 0; s2 >>= 1) {
        if (tid < s2) red[tid] += red[tid + s2];
        __syncthreads();
    }
    __shared__ float sa;
    if (tid == 0) { sa = fmaxf(red[0], 1e-7f); sums[r] = sa; }
    __syncthreads();
    if (w_t != nullptr) {
        float aa = sa;
        for (int i = tid; i < NRELC; i += 256) {
            float v = w_t[(size_t)r * NRELC + i] / aa;
            wsc[(size_t)r * NRELC + i] = v;
            if (wTg != nullptr && i < 2 * RR) wTg[(size_t)i * SROW + r] = v;
        }
    }
}

// ====== MERGED hop epilogue (48 blocks x 512): both halves depend only on the
// preceding hop_bucket -> run in one dispatch. Blocks 0..23: radix top-k on the
// compact list, write th, OR activity bits into the (pre-zeroed) next-hop mask,
// re-arm cursor. Blocks 24..47: reduce partial2 -> sums (exact 256-lane order
// preserved), emit wsc + wT for the next hop. No shared state between halves. ======
__global__ __launch_bounds__(512) void hop_epi(
    const unsigned* __restrict__ ckey, const unsigned* __restrict__ cent,
    unsigned* __restrict__ rowcnt, float* __restrict__ th,
    int* __restrict__ mask_next,
    const float* __restrict__ partial2, float* __restrict__ sums,
    const float* __restrict__ w_t, float* __restrict__ wsc,
    float* __restrict__ wTg)
{
    int tid = threadIdx.x;
    if (blockIdx.x >= 24) {                   // -------- rowsum_fin2 half --------
        int r = blockIdx.x - 24;
        __shared__ float red[256];
        __shared__ float sa;
        if (tid < 256) {                      // keep 256-lane reduce order (FP-stable)
            float a = 0.f;
            for (int g = tid; g < NBUCK; g += 256) a += partial2[(size_t)g * 24 + r];
            red[tid] = a;
        }
        __syncthreads();
        for (int s2 = 128; s2 > 0; s2 >>= 1) {
            if (tid < s2) red[tid] += red[tid + s2];
            __syncthreads();
        }
        if (tid == 0) { sa = fmaxf(red[0], 1e-7f); sums[r] = sa; }
        __syncthreads();
        float aa = sa;
        for (int i = tid; i < NRELC; i += 512) {
            float v = w_t[(size_t)r * NRELC + i] / aa;
            wsc[(size_t)r * NRELC + i] = v;
            if (i < 2 * RR) wTg[(size_t)i * SROW + r] = v;
        }
        return;
    }
    // -------- topk half --------
    int row = blockIdx.x;
    const unsigned* keys = ckey + (size_t)row * SEGS;
    int n = min((int)rowcnt[row], SEGS);
    __shared__ unsigned hist[256];
    __shared__ int red[256];
    __shared__ int sh_bin, sh_rem;
    unsigned prefix = 0;
    int remk = KTOP;
    int iters = (n + 511) / 512;
    int lane = tid & 63;
    for (int round = 0; round < 4; ++round) {
        if (tid < 256) hist[tid] = 0u;
        __syncthreads();
        int shift = 24 - 8 * round;
        for (int it = 0; it < iters; ++it) {
            int i = it * 512 + tid;
            bool valid = (i < n);
            unsigned key = valid ? keys[i] : 0u;
            valid = valid && (round == 0 || (key >> (shift + 8)) == prefix);
            unsigned bin = valid ? ((key >> shift) & 255u) : 0u;
            unsigned long long peers = __ballot(valid);
            #pragma unroll
            for (int bit = 0; bit < 8; ++bit) {
                unsigned long long bm = __ballot(valid && ((bin >> bit) & 1u));
                peers &= ((bin >> bit) & 1u) ? bm : ~bm;
            }
            if (valid) {
                unsigned long long lower = peers & ((1ull << lane) - 1ull);
                if (lower == 0ull)
                    atomicAdd(&hist[bin], (unsigned)__popcll(peers));
            }
        }
        __syncthreads();
        if (tid < 256) red[tid] = (int)hist[tid];
        __syncthreads();
        for (int off = 1; off < 256; off <<= 1) {   // inclusive suffix scan
            int v = 0;
            if (tid < 256 && tid + off < 256) v = red[tid + off];
            __syncthreads();
            if (tid < 256) red[tid] += v;
            __syncthreads();
        }
        if (tid == 0) { sh_bin = 0; sh_rem = remk; }  // default: k-th lies among zeros
        __syncthreads();
        if (tid < 256) {
            int cnt = (int)hist[tid];
            int above = (tid == 255) ? 0 : red[tid + 1];
            if (above < remk && above + cnt >= remk) { sh_bin = tid; sh_rem = remk - above; }
        }
        __syncthreads();
        prefix = (prefix << 8) | (unsigned)sh_bin;
        remk = sh_rem;
        __syncthreads();
    }
    if (tid == 0) th[row] = __uint_as_float(prefix);
    {
        const unsigned* ents = cent + (size_t)row * SEGS;
        int bit = 1 << (row / 3);
        for (int i = tid; i < n; i += 512) {
            if (keys[i] >= prefix) {
                unsigned e = ents[i];
                if (e < (unsigned)EE) atomicOr(&mask_next[e], bit);
            }
        }
        if (tid == 0) rowcnt[row] = 0u;       // re-arm compact cursor for next hop
    }
}

// ====== fallback topk (contiguous lists, zero+write same mask) ======
__global__ __launch_bounds__(512) void topk_select(
    const unsigned* __restrict__ ckey, unsigned* __restrict__ rowcnt,
    float* __restrict__ th, int* __restrict__ mask)
{
    int row = blockIdx.x, tid = threadIdx.x;
    {
        int per = (EE + 23) / 24;
        int e0 = row * per, e1 = min(e0 + per, EE);
        for (int e = e0 + tid; e < e1; e += 512) mask[e] = 0;
    }
    const unsigned* keys = ckey + (size_t)row * SEGS;
    int n = min((int)rowcnt[row], SEGS);
    __shared__ unsigned hist[256];
    __shared__ int red[256];
    __shared__ int sh_bin, sh_rem;
    unsigned prefix = 0;
    int remk = KTOP;
    int iters = (n + 511) / 512;
    int lane = tid & 63;
    for (int round = 0; round < 4; ++round) {
        if (tid < 256) hist[tid] = 0u;
        __syncthreads();
        int shift = 24 - 8 * round;
        for (int it = 0; it < iters; ++it) {
            int i = it * 512 + tid;
            bool valid = (i < n);
            unsigned key = valid ? keys[i] : 0u;
            valid = valid && (round == 0 || (key >> (shift + 8)) == prefix);
            unsigned bin = valid ? ((key >> shift) & 255u) : 0u;
            unsigned long long peers = __ballot(valid);
            #pragma unroll
            for (int bit = 0; bit < 8; ++bit) {
                unsigned long long bm = __ballot(valid && ((bin >> bit) & 1u));
                peers &= ((bin >> bit) & 1u) ? bm : ~bm;
            }
            if (valid) {
                unsigned long long lower = peers & ((1ull << lane) - 1ull);
                if (lower == 0ull)
                    atomicAdd(&hist[bin], (unsigned)__popcll(peers));
            }
        }
        __syncthreads();
        if (tid < 256) red[tid] = (int)hist[tid];
        __syncthreads();
        for (int off = 1; off < 256; off <<= 1) {
            int v = 0;
            if (tid < 256 && tid + off < 256) v = red[tid + off];
            __syncthreads();
            if (tid < 256) red[tid] += v;
            __syncthreads();
        }
        if (tid == 0) { sh_bin = 0; sh_rem = remk; }
        __syncthreads();
        if (tid < 256) {
            int cnt = (int)hist[tid];
            int above = (tid == 255) ? 0 : red[tid + 1];
            if (above < remk && above + cnt >= remk) { sh_bin = tid; sh_rem = remk - above; }
        }
        __syncthreads();
        prefix = (prefix << 8) | (unsigned)sh_bin;
        remk = sh_rem;
        __syncthreads();
    }
    if (tid == 0) th[row] = __uint_as_float(prefix);
}

// ======= fallback prune (writes x + identity-seeded s) =======
__global__ __launch_bounds__(256) void prune_flat(
    float* __restrict__ s, const float* __restrict__ th,
    const float* __restrict__ wsc, float* __restrict__ x, int* __restrict__ mask,
    unsigned* __restrict__ rowcnt, int write_s)
{
    __shared__ float ths[24], w4s[24];
    if (threadIdx.x < 24) {
        ths[threadIdx.x] = th[threadIdx.x];
        w4s[threadIdx.x] = wsc[threadIdx.x * NRELC + (NRELC - 1)];  // w400/sum
    }
    if (blockIdx.x == 0 && threadIdx.x < 24) rowcnt[threadIdx.x] = 0u;  // re-arm cursors
    __syncthreads();
    int i = blockIdx.x * 256 + threadIdx.x;
    if (i >= SROW * EE) return;
    int row = i % 24;
    int e = i / 24;
    float v = s[i];
    float xv = (v >= ths[row]) ? v : 0.f;
    x[i] = xv;
    if (write_s) s[i] = w4s[row] * xv;
    if (xv > 0.f) atomicOr(&mask[e], 1 << (row / 3));
}

// ============ FALLBACK (ws too small): fused masked scatter ============
__global__ __launch_bounds__(256) void hop_scan(
    const int* __restrict__ heads, const int* __restrict__ tails,
    const int* __restrict__ tails2, const int* __restrict__ rels,
    const int* __restrict__ mask, const float* __restrict__ x,
    const float* __restrict__ wsc, float* __restrict__ s)
{
    int gid = blockIdx.x * 256 + threadIdx.x;
    int i = gid >> 3;
    if (i >= NN) return;
    int b = gid & 7;
    int h = heads[i], t2 = tails2[i];
    int mh = mask[h], mt = mask[t2];
    bool ah = (mh >> b) & 1;
    bool at = (mt >> b) & 1;
    if (!(ah || at)) return;
    int tl = tails[i], rr = rels[i];
    int row = b * 3;
    if (ah) {
        float v0 = x[(size_t)h * SROW + row];
        float v1 = x[(size_t)h * SROW + row + 1];
        float v2 = x[(size_t)h * SROW + row + 2];
        if (v0 != 0.f) atomicAdd(&s[(size_t)tl * SROW + row],     v0 * wsc[(row)     * NRELC + rr]);
        if (v1 != 0.f) atomicAdd(&s[(size_t)tl * SROW + row + 1], v1 * wsc[(row + 1) * NRELC + rr]);
        if (v2 != 0.f) atomicAdd(&s[(size_t)tl * SROW + row + 2], v2 * wsc[(row + 2) * NRELC + rr]);
    }
    if (at) {
        float v0 = x[(size_t)t2 * SROW + row];
        float v1 = x[(size_t)t2 * SROW + row + 1];
        float v2 = x[(size_t)t2 * SROW + row + 2];
        if (v0 != 0.f) atomicAdd(&s[(size_t)h * SROW + row],     v0 * wsc[(row)     * NRELC + rr + RR]);
        if (v1 != 0.f) atomicAdd(&s[(size_t)h * SROW + row + 1], v1 * wsc[(row + 1) * NRELC + rr + RR]);
        if (v2 != 0.f) atomicAdd(&s[(size_t)h * SROW + row + 2], v2 * wsc[(row + 2) * NRELC + rr + RR]);
    }
}

// ========== staging build (csr_hist packed into pre_fused) ==========
__global__ __launch_bounds__(512) void csr_scanb(
    unsigned* __restrict__ bh, unsigned* __restrict__ gcnt)
{
    __shared__ unsigned sc[STB];
    int bk = blockIdx.x, tid = threadIdx.x;
    unsigned v = bh[(size_t)bk * STB + tid];
    sc[tid] = v; __syncthreads();
    #pragma unroll
    for (int o = 1; o < STB; o <<= 1) {
        unsigned u = (tid >= o) ? sc[tid - o] : 0u;
        __syncthreads();
        sc[tid] += u;
        __syncthreads();
    }
    bh[(size_t)bk * STB + tid] = sc[tid] - v;     // exclusive within bucket
    if (tid == STB - 1) gcnt[bk] = sc[tid];
}

__global__ __launch_bounds__(1024) void csr_scan2(
    const unsigned* __restrict__ gcnt, unsigned* __restrict__ gOff)
{
    __shared__ unsigned sc[1024];
    int tid = threadIdx.x;
    unsigned v = (tid < NBUCK) ? gcnt[tid] : 0u;
    sc[tid] = v; __syncthreads();
    #pragma unroll
    for (int o = 1; o < 1024; o <<= 1) {
        unsigned u = (tid >= o) ? sc[tid - o] : 0u;
        __syncthreads();
        sc[tid] += u;
        __syncthreads();
    }
    if (tid < NBUCK) gOff[tid] = sc[tid] - v;
    if (tid == NBUCK - 1) gOff[NBUCK] = sc[tid];
}

__global__ __launch_bounds__(256) void csr_stage2(
    const int* __restrict__ heads, const int* __restrict__ tails,
    const int* __restrict__ tails2, const int* __restrict__ rels,
    const unsigned* __restrict__ gOff, const unsigned* __restrict__ bh,
    unsigned* __restrict__ staging)
{
    __shared__ unsigned base[NBUCK];
    __shared__ unsigned cur[NBUCK];
    int tid = threadIdx.x;
    for (int j = tid; j < NBUCK; j += 256) {
        base[j] = gOff[j] + bh[(size_t)j * STB + blockIdx.x];
        cur[j] = 0u;
    }
    __syncthreads();
    for (int i = blockIdx.x * 256 + tid; i < NN; i += STB * 256) {
        unsigned rl = (unsigned)rels[i];
        int h = heads[i], d1 = tails[i], t2 = tails2[i];
        unsigned p1 = base[d1 >> BSH] + atomicAdd(&cur[d1 >> BSH], 1u);
        if (p1 < (unsigned)CSRN)
            staging[p1] = ((unsigned)(d1 & 63) << 26) | ((unsigned)h << 9) | rl;
        unsigned p2 = base[h >> BSH] + atomicAdd(&cur[h >> BSH], 1u);
        if (p2 < (unsigned)CSRN)
            staging[p2] = ((unsigned)(h & 63) << 26) | ((unsigned)t2 << 9) | (rl + RR);
    }
}

// ===== hops 0..2: bucket gather, fused identity+store+rowsum+compact =====
__global__ __launch_bounds__(256) void hop_bucket(
    const unsigned* __restrict__ gOff, const unsigned* __restrict__ staging,
    const int* __restrict__ mask, const float* __restrict__ sprev,
    const float* __restrict__ th, const int* __restrict__ input_x,
    const float* __restrict__ wT, const float* __restrict__ wsc,
    float* __restrict__ snext, float* __restrict__ partial2,
    unsigned* __restrict__ ckey, unsigned* __restrict__ cent,
    unsigned* __restrict__ rowcnt, int do_compact, int is_t0)
{
    __shared__ float sl[64][24];              // 6KB accumulation tile
    __shared__ float w4s[24];
    __shared__ float ths[24];
    __shared__ int   xs8[8];
    __shared__ float acc24[24];
    __shared__ unsigned lcnt[24];
    __shared__ unsigned lbase[24];
    __shared__ unsigned lkey[24][64];         // 6KB compact keys
    __shared__ unsigned lent[24][64];         // 6KB compact entities
    int bk = blockIdx.x, tid = threadIdx.x;
    for (int i = tid; i < 64 * 24; i += 256) ((float*)sl)[i] = 0.f;
    if (tid < 24) {
        w4s[tid] = wsc[tid * NRELC + (NRELC - 1)];
        ths[tid] = is_t0 ? 0.f : th[tid];
        acc24[tid] = 0.f;
        lcnt[tid] = 0u;
    }
    if (tid < 8) xs8[tid] = is_t0 ? input_x[tid] : 0;
    __syncthreads();
    unsigned j0 = gOff[bk], j1 = gOff[bk + 1];
    for (unsigned j = j0 + tid; j < j1; j += 256) {
        unsigned p = staging[j];
        int src = (int)((p >> 9) & 0xFFFFu);
        int m = mask[src];
        if (!m) continue;
        int dl = (int)(p >> 26);
        int rel = (int)(p & 511u);
        const float* wr = wT + (size_t)rel * SROW;
        if (is_t0) {
            while (m) {
                int b = __ffs(m) - 1; m &= m - 1;
                int r = b * 3;
                atomicAdd(&sl[dl][r],     wr[r]);
                atomicAdd(&sl[dl][r + 1], wr[r + 1]);
                atomicAdd(&sl[dl][r + 2], wr[r + 2]);
            }
        } else {
            const float* xsrow = sprev + (size_t)src * SROW;
            while (m) {
                int b = __ffs(m) - 1; m &= m - 1;
                int r = b * 3;
                float x0 = xsrow[r];     x0 = (x0 >= ths[r])     ? x0 : 0.f;
                float x1 = xsrow[r + 1]; x1 = (x1 >= ths[r + 1]) ? x1 : 0.f;
                float x2 = xsrow[r + 2]; x2 = (x2 >= ths[r + 2]) ? x2 : 0.f;
                atomicAdd(&sl[dl][r],     x0 * wr[r]);
                atomicAdd(&sl[dl][r + 1], x1 * wr[r + 1]);
                atomicAdd(&sl[dl][r + 2], x2 * wr[r + 2]);
            }
        }
    }
    __syncthreads();
    int e0 = bk * 64;
    for (int idx = tid; idx < 64 * 24; idx += 256) {
        int el = idx / 24, row = idx % 24;    // idx order == s layout -> coalesced store
        int e = e0 + el;
        if (e >= EE) continue;
        float xv;
        if (is_t0) {
            xv = (e == xs8[row / 3]) ? 1.f : 0.f;
        } else {
            float u = sprev[(size_t)e * SROW + row];
            xv = (u >= ths[row]) ? u : 0.f;
        }
        float v = sl[el][row] + w4s[row] * xv;
        snext[(size_t)e * SROW + row] = v;
        atomicAdd(&acc24[row], v);            // LDS
        if (do_compact && __float_as_uint(v) != 0u) {
            unsigned slot = atomicAdd(&lcnt[row], 1u);
            slot = min(slot, 63u);            // defensive (invariant: <=64)
            lkey[row][slot] = __float_as_uint(v);
            lent[row][slot] = (unsigned)e;
        }
    }
    __syncthreads();
    if (tid < 24) partial2[(size_t)bk * 24 + tid] = acc24[tid];
    if (do_compact) {
        if (tid < 24) {
            unsigned c = min(lcnt[tid], 64u);
            lcnt[tid] = c;
            lbase[tid] = min(atomicAdd(&rowcnt[tid], c), (unsigned)SEGS);
        }
        __syncthreads();
        int r = tid % 24;
        int nthr = (r < 16) ? 11 : 10;
        unsigned cnt = lcnt[r], base = lbase[r];
        if (base + cnt > (unsigned)SEGS) cnt = (unsigned)SEGS - base;   // defensive
        for (unsigned j = (unsigned)(tid / 24); j < cnt; j += nthr) {
            ckey[(size_t)r * SEGS + base + j] = lkey[r][j];
            cent[(size_t)r * SEGS + base + j] = lent[r][j];
        }
    }
}

// ================= final (e-major, normalizes on the fly) =================
__global__ void final_kernel(const float* __restrict__ s, const float* __restrict__ sums,
                             float* __restrict__ out) {
    __shared__ float ss[24];
    if (threadIdx.x < 24) ss[threadIdx.x] = sums[threadIdx.x];
    __syncthreads();
    int e = blockIdx.x * 256 + threadIdx.x;
    if (e >= EE) return;
    const float* se = s + (size_t)e * SROW;
    #pragma unroll
    for (int b = 0; b < 8; ++b)
        out[(size_t)b * EE + e] = se[b * 3] / ss[b * 3]
                                + se[b * 3 + 1] / ss[b * 3 + 1]
                                + se[b * 3 + 2] / ss[b * 3 + 2];
}

extern "C" void kernel_launch(void* const* d_in, const int* in_sizes, int n_in,
                              void* d_out, int out_size, void* d_ws, size_t ws_size,
                              hipStream_t stream)
{
    const int*   input_x  = (const int*)d_in[0];
    const int*   input_r  = (const int*)d_in[1];
    const int*   e2triple = (const int*)d_in[2];
    const int*   triple2e = (const int*)d_in[3];
    const int*   r2triple = (const int*)d_in[4];
    const float* emb      = (const float*)d_in[5];
    const float* Wih_f    = (const float*)d_in[6];
    const float* Whh_f    = (const float*)d_in[7];
    const float* bih_f    = (const float*)d_in[8];
    const float* bhh_f    = (const float*)d_in[9];
    const float* Wih_b    = (const float*)d_in[10];
    const float* Whh_b    = (const float*)d_in[11];
    const float* bih_b    = (const float*)d_in[12];
    const float* bhh_b    = (const float*)d_in[13];
    const float* linW     = (const float*)d_in[14];
    const float* linb     = (const float*)d_in[15];

    const int* heads  = e2triple;
    const int* tails2 = e2triple + 2 * (size_t)NN;
    const int* tails  = triple2e + (size_t)NN;
    const int* rels   = r2triple;

    // workspace layout (~30 MB; poison fill shows ws >= 256 MB)
    float* ws      = (float*)d_ws;
    float* hbuf    = ws;                          // 36864
    float* wbuf    = hbuf + 36864;                // 28872
    float* sstA    = wbuf + 28872;                // 1200000 (e-major [E][24])
    float* sstB    = sstA + 1200000;              // 1200000
    float* sums    = sstB + 1200000;              // 24
    float* th      = sums + 24;                   // 24
    int*   maskT0  = (int*)(th + 24);             // 50000
    int*   maskT1  = maskT0 + EE;                 // 50000
    int*   maskT2  = maskT1 + EE;                 // 50000
    float* partial = (float*)(maskT2 + EE);       // 384*24 = 9216
    unsigned* rowcnt  = (unsigned*)(partial + 9216);  // 32
    float* partial2   = (float*)(rowcnt + 32);    // 782*24 = 18768
    unsigned* ckey    = (unsigned*)(partial2 + NBUCK * 24); // 24*50176 = 1,204,224
    unsigned* cent    = ckey + 24 * (size_t)SEGS; // 1,204,224 compact entity IDs
    unsigned* bh      = cent + 24 * (size_t)SEGS; // 782*512 = 400,384
    unsigned* gcnt    = bh + (size_t)NBUCK * STB; // 784
    unsigned* gOff    = gcnt + 784;               // 800 (NBUCK+1 used)
    unsigned* staging = gOff + 800;               // 2,000,000 (own region)
    float*    wT      = (float*)(staging + CSRN); // 9600 transposed scaled weights
    float*    wT0     = wT + 9600;                // 9600 transposed UNSCALED t0 weights
    const size_t NEED = (size_t)((wT0 + 9600) - ws) * 4;
    const bool use_csr = (ws_size >= NEED);
    // aliases (phase-A scratch inside sstA; dead before hop_bucket t0 writes it)
    float* wsc     = hbuf;                        // 9624, dead after logits_dot
    float* preq    = sstA;                        // 49152
    float* pree    = preq + 49152;                // 6144
    float* hstateA = pree + 6144;                 // 12288
    float* hstateB = hstateA + 12288;             // 12288
    float* cstate  = hstateB + 12288;             // 12288

    float* out = (float*)d_out;
    const int EBLK  = (EE + 255) / 256;           // 196
    const int SBLK  = (SROW * EE + 255) / 256;    // 4688
    const int NBLK  = (NN + 255) / 256;           // 3907
    const int N8BLK = (NN * 8) / 256;             // 31250

    // ---- Phase A (fused LSTM cell updates; csr_hist packed into pre_fused) ----
    pre_fused<<<896, 256, 0, stream>>>(input_r, emb, Wih_f, bih_f, bhh_f,
                                       Wih_b, bih_b, bhh_b, preq, pree,
                                       hstateA, cstate, hbuf,
                                       heads, tails, bh, use_csr ? 1 : 0);
    rec_fused<<<384, 256, 0, stream>>>(Whh_f, Whh_b, preq, pree, hstateA, hstateB,
                                       cstate, hbuf, 1);
    rec_fused<<<384, 256, 0, stream>>>(Whh_f, Whh_b, preq, pree, hstateB, hstateA,
                                       cstate, hbuf, 2);
    rec_fused<<<384, 256, 0, stream>>>(Whh_f, Whh_b, preq, pree, hstateA, hstateB,
                                       cstate, hbuf, 3);
    logits_dot<<<903, 256, 0, stream>>>(hbuf, linW, linb, wbuf);

    if (use_csr) {
        // softmax + packed mask init (maskT0 bits; zero maskT1/T2; arm cursors)
        softmax_kernel<<<72 + EBLK, 256, 0, stream>>>(wbuf, wT0, maskT0, maskT1, maskT2,
                                                      input_x, rowcnt);
        // ---- staging build (hist already done inside pre_fused) ----
        csr_scanb<<<NBUCK, 512, 0, stream>>>(bh, gcnt);
        csr_scan2<<<1, 1024, 0, stream>>>(gcnt, gOff);
        csr_stage2<<<STB, 256, 0, stream>>>(heads, tails, tails2, rels, gOff, bh, staging);
        // ---- hop 0: bucket gather with virtual one-hot input ----
        hop_bucket<<<NBUCK, 256, 0, stream>>>(gOff, staging, maskT0, nullptr, nullptr,
                                              input_x, wT0, wbuf, sstA, partial2,
                                              ckey, cent, rowcnt, 1, 1);
        hop_epi<<<48, 512, 0, stream>>>(ckey, cent, rowcnt, th, maskT1,
                                        partial2, sums, wbuf + 1 * 24 * NRELC, wsc, wT);
        // t=1: sstA -> sstB
        hop_bucket<<<NBUCK, 256, 0, stream>>>(gOff, staging, maskT1, sstA, th,
                                              input_x, wT, wsc, sstB, partial2,
                                              ckey, cent, rowcnt, 1, 0);
        hop_epi<<<48, 512, 0, stream>>>(ckey, cent, rowcnt, th, maskT2,
                                        partial2, sums, wbuf + 2 * 24 * NRELC, wsc, wT);
        // t=2: sstB -> sstA
        hop_bucket<<<NBUCK, 256, 0, stream>>>(gOff, staging, maskT2, sstB, th,
                                              input_x, wT, wsc, sstA, partial2,
                                              ckey, cent, rowcnt, 0, 0);
        rowsum_fin2<<<24, 256, 0, stream>>>(partial2, sums, nullptr, nullptr, nullptr);
        final_kernel<<<EBLK, 256, 0, stream>>>(sstA, sums, out);
    } else {
        softmax_kernel<<<72, 256, 0, stream>>>(wbuf, nullptr, nullptr, nullptr, nullptr,
                                               input_x, rowcnt);
        // ---- fallback: proven scatter path (xst = sstA as x buffer) ----
        float* xst = sstA;
        float* sst = sstB;
        int* mask = maskT0;
        fill_seed<<<SBLK, 256, 0, stream>>>(sst, input_x, wbuf, rowcnt);
        hop0_scan<<<NBLK, 256, 0, stream>>>(heads, tails, tails2, rels, input_x, wbuf, sst);
        rowsum_compact<<<384, 256, 0, stream>>>(sst, partial, ckey, rowcnt, 1);
        rowsum_fin<<<24, 256, 0, stream>>>(partial, sums, wbuf + 1 * 24 * NRELC, wsc, nullptr);
        for (int t = 1; t < TT; ++t) {
            topk_select<<<24, 512, 0, stream>>>(ckey, rowcnt, th, mask);
            prune_flat<<<SBLK, 256, 0, stream>>>(sst, th, wsc, xst, mask, rowcnt, 1);
            hop_scan<<<N8BLK, 256, 0, stream>>>(heads, tails, tails2, rels, mask, xst, wsc, sst);
            rowsum_compact<<<384, 256, 0, stream>>>(sst, partial, ckey, rowcnt,
                                                    (t + 1 < TT) ? 1 : 0);
            const float* w_next = (t + 1 < TT) ? (wbuf + (size_t)(t + 1) * 24 * NRELC) : nullptr;
            rowsum_fin<<<24, 256, 0, stream>>>(partial, sums, w_next, wsc, nullptr);
        }
        final_kernel<<<EBLK, 256, 0, stream>>>(sst, sums, out);
    }
}